// Round 5
// baseline (794.570 us; speedup 1.0000x reference)
//
#include <hip/hip_runtime.h>
#include <math.h>

// NoisyEmbedding: argmax_j( cos_sim(w[ids[i]], w[j]) + 20*gumbel[i][j] ) -> gather w[argmax]
//
// sims span <= 2, so only j with gumbel g within 0.1 of the row max can win
// (20*0.1 = 2). g = -log(-log u) is monotone in u -> stream gumbel_u once in
// the u-domain, keep per-chunk survivors within 0.1001 of the chunk-segment
// max (superset of the exact candidate set), rescore survivors exactly in
// f32, argmax with first-index tie-break (matches jnp.argmax).
//
// Fusion WITHOUT cooperative launch (round 4's coop launch failed): per-chunk
// candidate lists + an acq_rel countdown prog[row]; the block that completes
// a row's last chunk scores that row inline. Scoring overlaps scanning.

constexpr int V  = 50257;
constexpr int D  = 768;
constexpr int BT = 2048;
constexpr long TOTAL = (long)BT * V;            // 102,926,336 (fits int32)
constexpr int ITOTAL = (int)TOTAL;
constexpr int NF4    = ITOTAL >> 2;             // TOTAL % 4 == 0
constexpr int LOG2C  = 13;
constexpr int CHUNK  = 1 << LOG2C;              // 8192 elements per chunk
constexpr int NBLK   = (ITOTAL + CHUNK - 1) / CHUNK;  // 12565
constexpr int CCAP   = 32;                      // per-chunk survivor cap (E ~ 2.1)
constexpr float KPOW = 1.1052847f;              // expf(0.1001)
constexpr float TWO_OVER_EPS = 20.0f;

typedef float f32x4 __attribute__((ext_vector_type(4)));

__device__ __forceinline__ int total_chunks(int r) {
  return ((((r + 1) * V - 1) >> LOG2C) - ((r * V) >> LOG2C)) + 1;  // <= 8
}

struct ScoreLds {          // ~6.2 KB
  float q[D];
  float lu[256];
  float lsc[256];
  int   li[256];
  float red[4];
  float invq;
  int   n, sel;
};

__device__ __forceinline__ void score_row(
    int r, const float* __restrict__ w, const int* __restrict__ ids,
    const int* ccnt, const int* cflat, const float* cuv,
    float* __restrict__ out, ScoreLds* S, int tid, int lane, int wid) {
  if (tid == 0) S->n = 0;
  __syncthreads();
  // collect row r's candidates from its <=8 chunk lists (agent loads)
  int c0 = (r * V) >> LOG2C, c1 = (((r + 1) * V) - 1) >> LOG2C;
  int nch = c1 - c0 + 1;
  if (tid < nch) {
    int c = c0 + tid;
    int m = __hip_atomic_load(&ccnt[c], __ATOMIC_RELAXED, __HIP_MEMORY_SCOPE_AGENT);
    if (m > CCAP) m = CCAP;
    int lo = r * V, hi = lo + V;
    for (int k = 0; k < m; ++k) {
      int fx = __hip_atomic_load(&cflat[c * CCAP + k], __ATOMIC_RELAXED,
                                 __HIP_MEMORY_SCOPE_AGENT);
      if (fx >= lo && fx < hi) {               // list may hold the other row too
        int p = atomicAdd(&S->n, 1);           // LDS atomic
        S->li[p] = fx - lo;
        S->lu[p] = __hip_atomic_load(&cuv[c * CCAP + k], __ATOMIC_RELAXED,
                                     __HIP_MEMORY_SCOPE_AGENT);
      }
    }
  }
  // stage q into LDS + inv-norm (concurrent with collection; disjoint LDS)
  int qid = ids[r];
  float qs = 0.f;
#pragma unroll
  for (int k = 0; k < 3; ++k) {
    float x = w[(size_t)qid * D + k * 256 + tid];
    S->q[k * 256 + tid] = x;
    qs += x * x;
  }
#pragma unroll
  for (int off = 32; off > 0; off >>= 1) qs += __shfl_down(qs, off, 64);
  if (lane == 0) S->red[wid] = qs;
  __syncthreads();
  if (tid == 0)
    S->invq = 1.0f / fmaxf(sqrtf(S->red[0] + S->red[1] + S->red[2] + S->red[3]), 1e-12f);
  __syncthreads();
  float invq = S->invq;
  int n = S->n; if (n > 256) n = 256;

  for (int cI = wid; cI < n; cI += 4) {        // one wave per candidate
    int j = S->li[cI];
    const float4* p  = reinterpret_cast<const float4*>(w + (size_t)j * D);
    const float4* qp = reinterpret_cast<const float4*>(S->q);
    float dot = 0.f, n2 = 0.f;
#pragma unroll
    for (int k = 0; k < 3; ++k) {
      float4 a = p[k * 64 + lane];
      float4 b = qp[k * 64 + lane];
      dot += a.x * b.x + a.y * b.y + a.z * b.z + a.w * b.w;
      n2  += a.x * a.x + a.y * a.y + a.z * a.z + a.w * a.w;
    }
#pragma unroll
    for (int off = 32; off > 0; off >>= 1) {
      dot += __shfl_down(dot, off, 64);
      n2  += __shfl_down(n2,  off, 64);
    }
    if (lane == 0) {
      float invj = 1.0f / fmaxf(sqrtf(n2), 1e-12f);
      float uu = S->lu[cI];
      S->lsc[cI] = invq * invj * dot + TWO_OVER_EPS * (-logf(-logf(uu)));
    }
  }
  __syncthreads();

  if (wid == 0) {                              // argmax: (score desc, idx asc)
    float bs = -INFINITY;
    int bj = 0x7fffffff;
    for (int cI = lane; cI < n; cI += 64) {
      float s = S->lsc[cI];
      int j = S->li[cI];
      if (s > bs || (s == bs && j < bj)) { bs = s; bj = j; }
    }
#pragma unroll
    for (int off = 32; off > 0; off >>= 1) {
      float os = __shfl_down(bs, off, 64);
      int   oj = __shfl_down(bj, off, 64);
      if (os > bs || (os == bs && oj < bj)) { bs = os; bj = oj; }
    }
    if (lane == 0) S->sel = bj;
  }
  __syncthreads();

  int sel = S->sel;
#pragma unroll
  for (int k = 0; k < 3; ++k)
    out[(size_t)r * D + k * 256 + tid] = w[(size_t)sel * D + k * 256 + tid];
  __syncthreads();                             // LDS reused by a 2nd score_row
}

__global__ __launch_bounds__(256) void k_fused(
    const float* __restrict__ gum, const float* __restrict__ w,
    const int* __restrict__ ids, int* ccnt, int* cflat, float* cuv,
    int* prog, float* __restrict__ out) {
  __shared__ float slo[4], shi[4];
  __shared__ float s_tlo, s_thi;
  __shared__ int s_cnt, s_do0, s_do1;
  __shared__ ScoreLds S;

  int tid = threadIdx.x, b = blockIdx.x;
  int lane = tid & 63, wid = tid >> 6;
  int start = b * CHUNK;
  int end = start + CHUNK; if (end > ITOTAL) end = ITOTAL;
  int row0 = start / V;                        // compile-time magic-mul
  int bnd  = (row0 + 1) * V;
  bool hasHi = end > bnd;                      // chunk straddles <=1 row boundary

  if (tid == 0) s_cnt = 0;

  const f32x4* g4 = reinterpret_cast<const f32x4*>(gum);
  int f4base = start >> 2;
  f32x4 v[8];
#pragma unroll
  for (int k = 0; k < 8; ++k) {
    int fi = f4base + k * 256 + tid;
    if (fi < NF4) v[k] = __builtin_nontemporal_load(&g4[fi]);
    else          v[k] = (f32x4){-1.f, -1.f, -1.f, -1.f};
  }
  float mlo = -1.f, mhi = -1.f;
  if (hasHi) {                                 // block-uniform branch
#pragma unroll
    for (int k = 0; k < 8; ++k) {
      int e0 = (f4base + k * 256 + tid) << 2;
#pragma unroll
      for (int j = 0; j < 4; ++j) {
        if (e0 + j < bnd) mlo = fmaxf(mlo, v[k][j]);
        else              mhi = fmaxf(mhi, v[k][j]);
      }
    }
  } else {
#pragma unroll
    for (int k = 0; k < 8; ++k)
#pragma unroll
      for (int j = 0; j < 4; ++j) mlo = fmaxf(mlo, v[k][j]);
  }
#pragma unroll
  for (int off = 32; off > 0; off >>= 1) {
    mlo = fmaxf(mlo, __shfl_down(mlo, off, 64));
    mhi = fmaxf(mhi, __shfl_down(mhi, off, 64));
  }
  if (lane == 0) { slo[wid] = mlo; shi[wid] = mhi; }
  __syncthreads();                             // also publishes s_cnt = 0
  if (tid == 0) {
    float a = fmaxf(fmaxf(slo[0], slo[1]), fmaxf(slo[2], slo[3]));
    float c = fmaxf(fmaxf(shi[0], shi[1]), fmaxf(shi[2], shi[3]));
    // g >= g_segmax - 0.1001  <=>  u >= u_segmax^KPOW (u in (0,1]).
    // Empty hi segment: max=-1 -> NaN threshold, but then no element uses it.
    s_tlo = expf(KPOW * logf(a));
    s_thi = expf(KPOW * logf(c));
  }
  __syncthreads();
  float tlo = s_tlo, thi = s_thi;
#pragma unroll
  for (int k = 0; k < 8; ++k) {
    int e0 = (f4base + k * 256 + tid) << 2;
#pragma unroll
    for (int j = 0; j < 4; ++j) {
      int idx = e0 + j;
      float uu = v[k][j];
      bool lo = idx < bnd;
      if (uu >= (lo ? tlo : thi)) {            // OOB lanes: -1 vs NaN/pos -> false
        int p = atomicAdd(&s_cnt, 1);          // LDS atomic
        if (p < CCAP) {
          __hip_atomic_store(&cflat[b * CCAP + p], idx, __ATOMIC_RELAXED,
                             __HIP_MEMORY_SCOPE_AGENT);
          __hip_atomic_store(&cuv[b * CCAP + p], uu, __ATOMIC_RELAXED,
                             __HIP_MEMORY_SCOPE_AGENT);
        }
      }
    }
  }
  __syncthreads();   // all waves drain vmcnt before s_barrier -> stores complete
  if (tid == 0) {
    int m = s_cnt; if (m > CCAP) m = CCAP;
    __hip_atomic_store(&ccnt[b], m, __ATOMIC_RELAXED, __HIP_MEMORY_SCOPE_AGENT);
    // release publishes this block's list; acquire (same RMW) on the final
    // increment makes ALL chunks' lists visible to the scoring block.
    int d0 = __hip_atomic_fetch_add(&prog[row0], 1, __ATOMIC_ACQ_REL,
                                    __HIP_MEMORY_SCOPE_AGENT) + 1;
    s_do0 = (d0 == total_chunks(row0));
    int dd = 0;
    if (hasHi) {
      int d1 = __hip_atomic_fetch_add(&prog[row0 + 1], 1, __ATOMIC_ACQ_REL,
                                      __HIP_MEMORY_SCOPE_AGENT) + 1;
      dd = (d1 == total_chunks(row0 + 1));
    }
    s_do1 = dd;
  }
  __syncthreads();
  if (s_do0) score_row(row0,     w, ids, ccnt, cflat, cuv, out, &S, tid, lane, wid);
  if (s_do1) score_row(row0 + 1, w, ids, ccnt, cflat, cuv, out, &S, tid, lane, wid);
}

extern "C" void kernel_launch(void* const* d_in, const int* in_sizes, int n_in,
                              void* d_out, int out_size, void* d_ws, size_t ws_size,
                              hipStream_t stream) {
  const int*   ids = (const int*)d_in[0];    // input_ids (B*T)
  const float* w   = (const float*)d_in[1];  // weight (V*D)
  const float* gum = (const float*)d_in[2];  // gumbel_u (BT*V)
  float* out = (float*)d_out;

  char* ws = (char*)d_ws;
  int*   prog  = (int*)ws;                             // BT ints (memset each call)
  int*   ccnt  = (int*)(ws + 8192);                    // NBLK ints (written each call)
  int*   cflat = (int*)(ws + 59392);                   // NBLK*CCAP ints
  float* cuv   = (float*)(ws + 59392 + NBLK * CCAP * 4); // NBLK*CCAP floats
  // total ws use ~3.3 MB

  (void)hipMemsetAsync(prog, 0, BT * sizeof(int), stream);  // countdown reset
  k_fused<<<NBLK, 256, 0, stream>>>(gum, w, ids, ccnt, cflat, cuv, prog, out);
}

// Round 6
// 94.726 us; speedup vs baseline: 8.3881x; 8.3881x over previous
//
#include <hip/hip_runtime.h>
#include <math.h>

// NoisyEmbedding: argmax_j( cos_sim(w[ids[i]], w[j]) + 20*gumbel[i][j] ) -> gather w[argmax]
//
// sims span <= 2, so only j with gumbel g within 0.1 of its segment max can
// win (20*0.1 = 2). g = -log(-log u) is monotone in u -> stream gumbel_u in
// the u-domain, keep per-segment survivors with u >= u_segmax^exp(0.1001)
// (superset of the exact candidate set), rescore survivors exactly in f32,
// argmax with first-index tie-break (matches jnp.argmax).
//
// Round 5 post-mortem: agent-scope acq_rel atomics on non-coherent per-XCD
// L2s serialized the chip (9x). This round: two plain kernels (boundary =
// coherence), ZERO global atomics, ZERO memsets. Scan is per-WAVE independent
// (no __syncthreads, no LDS): ballot-compaction into per-wave-chunk lists.

constexpr int V  = 50257;
constexpr int D  = 768;
constexpr int BT = 2048;
constexpr long TOTAL = (long)BT * V;            // 102,926,336 (fits int32)
constexpr int ITOTAL = (int)TOTAL;
constexpr int NF4    = ITOTAL >> 2;             // TOTAL % 4 == 0
constexpr int LOG2C  = 12;
constexpr int WCHUNK = 1 << LOG2C;              // 4096 elems per wave
constexpr int NWC    = (ITOTAL + WCHUNK - 1) / WCHUNK;  // 25129 wave-chunks
constexpr int CCAP   = 16;                      // per-chunk survivor cap (E ~ 1.1)
constexpr float KPOW = 1.1052847f;              // expf(0.1001)
constexpr float TWO_OVER_EPS = 20.0f;

typedef float f32x4 __attribute__((ext_vector_type(4)));

// --- K1: per-wave scan. 16 x f32x4 per lane, segment maxima via shfl_xor
//         butterfly, ballot-compacted survivor stores. No atomics, no LDS. ---
__global__ __launch_bounds__(256) void k_scan(const float* __restrict__ gum,
                                              int* __restrict__ ccnt,
                                              int* __restrict__ cflat,
                                              float* __restrict__ cuv) {
  int tid  = threadIdx.x;
  int lane = tid & 63;
  int wc   = blockIdx.x * 4 + (tid >> 6);
  if (wc >= NWC) return;                        // wave-uniform exit

  int start  = wc * WCHUNK;
  int row0   = start / V;                       // compile-time magic-div
  int bnd    = (row0 + 1) * V;                  // <=1 row boundary per chunk
  int f4base = start >> 2;

  const f32x4* g4 = reinterpret_cast<const f32x4*>(gum);
  f32x4 v[16];
#pragma unroll
  for (int k = 0; k < 16; ++k) {                // 1KB/wave/instr, coalesced
    int fi = f4base + k * 64 + lane;
    if (fi < NF4) v[k] = __builtin_nontemporal_load(&g4[fi]);
    else          v[k] = (f32x4){-1.f, -1.f, -1.f, -1.f};
  }

  float mlo = -1.f, mhi = -1.f;                 // segment maxima (u in (0,1))
#pragma unroll
  for (int k = 0; k < 16; ++k) {
    int e0 = (f4base + k * 64 + lane) << 2;
#pragma unroll
    for (int j = 0; j < 4; ++j) {
      if (e0 + j < bnd) mlo = fmaxf(mlo, v[k][j]);
      else              mhi = fmaxf(mhi, v[k][j]);
    }
  }
#pragma unroll
  for (int off = 1; off < 64; off <<= 1) {      // butterfly: all lanes get max
    mlo = fmaxf(mlo, __shfl_xor(mlo, off, 64));
    mhi = fmaxf(mhi, __shfl_xor(mhi, off, 64));
  }
  // g >= g_segmax - 0.1001  <=>  u >= u_segmax^KPOW (u in (0,1]).
  // Empty segment: max = -1 -> logf(-1) = NaN -> threshold NaN -> all false.
  float tlo = expf(KPOW * logf(mlo));
  float thi = expf(KPOW * logf(mhi));

  int base = 0;                                 // wave-uniform running count
#pragma unroll
  for (int k = 0; k < 16; ++k) {
    int e0 = (f4base + k * 64 + lane) << 2;
#pragma unroll
    for (int j = 0; j < 4; ++j) {
      int idx = e0 + j;
      float uu = v[k][j];
      bool pred = uu >= ((idx < bnd) ? tlo : thi);  // OOB lanes: -1 -> false
      unsigned long long mask = __ballot(pred);
      if (pred) {
        int p = base + __popcll(mask & ((1ull << lane) - 1ull));
        if (p < CCAP) {
          cflat[wc * CCAP + p] = idx;
          cuv[wc * CCAP + p]   = uu;
        }
      }
      base += __popcll(mask);
    }
  }
  if (lane == 0) ccnt[wc] = (base < CCAP) ? base : CCAP;  // written every call
}

// --- K2: per row, collect candidates from <=14 chunk lists, exact f32
//         rescore (norms on the fly) + lexicographic argmax + gather. ---
__global__ __launch_bounds__(256) void k_score(const float* __restrict__ w,
                                               const int* __restrict__ ids,
                                               const int* __restrict__ ccnt,
                                               const int* __restrict__ cflat,
                                               const float* __restrict__ cuv,
                                               float* __restrict__ out) {
  __shared__ __align__(16) float q[D];
  __shared__ float lu[256], lsc[256];
  __shared__ int   li[256];
  __shared__ float s_red[4];
  __shared__ float s_invq;
  __shared__ int   s_n, s_sel;
  int row = blockIdx.x;
  int tid = threadIdx.x;
  int lane = tid & 63, wid = tid >> 6;

  if (tid == 0) s_n = 0;
  __syncthreads();

  // collect this row's candidates from its chunk lists (parallel over chunks)
  int c0 = (row * V) >> LOG2C;
  int c1 = (((row + 1) * V) - 1) >> LOG2C;
  int nch = c1 - c0 + 1;                        // <= 14
  if (tid < nch) {
    int c = c0 + tid;
    int m = ccnt[c]; if (m > CCAP) m = CCAP;
    int lo = row * V, hi = lo + V;
    for (int k = 0; k < m; ++k) {
      int fx = cflat[c * CCAP + k];
      if (fx >= lo && fx < hi) {                // list may hold neighbor row
        int p = atomicAdd(&s_n, 1);             // LDS atomic
        if (p < 256) { li[p] = fx - lo; lu[p] = cuv[c * CCAP + k]; }
      }
    }
  }
  // stage q + inv-norm (disjoint LDS, concurrent with collection)
  int qid = ids[row];
  float qs = 0.f;
#pragma unroll
  for (int k = 0; k < 3; ++k) {
    float x = w[(size_t)qid * D + k * 256 + tid];
    q[k * 256 + tid] = x;
    qs += x * x;
  }
#pragma unroll
  for (int off = 32; off > 0; off >>= 1) qs += __shfl_down(qs, off, 64);
  if (lane == 0) s_red[wid] = qs;
  __syncthreads();
  if (tid == 0)
    s_invq = 1.0f / fmaxf(sqrtf(s_red[0] + s_red[1] + s_red[2] + s_red[3]), 1e-12f);
  __syncthreads();
  float invq = s_invq;
  int n = s_n; if (n > 256) n = 256;

  for (int cI = wid; cI < n; cI += 4) {         // one wave per candidate
    int j = li[cI];
    const float4* p  = reinterpret_cast<const float4*>(w + (size_t)j * D);
    const float4* qp = reinterpret_cast<const float4*>(q);
    float dot = 0.f, n2 = 0.f;
#pragma unroll
    for (int k = 0; k < 3; ++k) {
      float4 a = p[k * 64 + lane];
      float4 b = qp[k * 64 + lane];
      dot += a.x * b.x + a.y * b.y + a.z * b.z + a.w * b.w;
      n2  += a.x * a.x + a.y * a.y + a.z * a.z + a.w * a.w;
    }
#pragma unroll
    for (int off = 32; off > 0; off >>= 1) {
      dot += __shfl_down(dot, off, 64);
      n2  += __shfl_down(n2,  off, 64);
    }
    if (lane == 0) {
      float invj = 1.0f / fmaxf(sqrtf(n2), 1e-12f);
      float uu = lu[cI];
      lsc[cI] = invq * invj * dot + TWO_OVER_EPS * (-logf(-logf(uu)));
    }
  }
  __syncthreads();

  if (wid == 0) {                               // argmax: (score desc, idx asc)
    float bs = -INFINITY;
    int bj = 0x7fffffff;
    for (int cI = lane; cI < n; cI += 64) {
      float s = lsc[cI];
      int j = li[cI];
      if (s > bs || (s == bs && j < bj)) { bs = s; bj = j; }
    }
#pragma unroll
    for (int off = 32; off > 0; off >>= 1) {
      float os = __shfl_down(bs, off, 64);
      int   oj = __shfl_down(bj, off, 64);
      if (os > bs || (os == bs && oj < bj)) { bs = os; bj = oj; }
    }
    if (lane == 0) s_sel = bj;
  }
  __syncthreads();

  int sel = s_sel;
#pragma unroll
  for (int k = 0; k < 3; ++k)
    out[(size_t)row * D + k * 256 + tid] = w[(size_t)sel * D + k * 256 + tid];
}

extern "C" void kernel_launch(void* const* d_in, const int* in_sizes, int n_in,
                              void* d_out, int out_size, void* d_ws, size_t ws_size,
                              hipStream_t stream) {
  const int*   ids = (const int*)d_in[0];    // input_ids (B*T)
  const float* w   = (const float*)d_in[1];  // weight (V*D)
  const float* gum = (const float*)d_in[2];  // gumbel_u (BT*V)
  float* out = (float*)d_out;

  char* ws = (char*)d_ws;
  int*   ccnt  = (int*)ws;                               // NWC ints (rewritten each call)
  int*   cflat = (int*)(ws + NWC * 4);                   // NWC*CCAP ints
  float* cuv   = (float*)(ws + NWC * 4 + NWC * CCAP * 4);// NWC*CCAP floats
  // ~3.3 MB of ws; no zeroing needed (ccnt fully rewritten every call)

  k_scan<<<(NWC + 3) / 4, 256, 0, stream>>>(gum, ccnt, cflat, cuv);
  k_score<<<BT, 256, 0, stream>>>(w, ids, ccnt, cflat, cuv, out);
}

// Round 7
// 78.696 us; speedup vs baseline: 10.0967x; 1.2037x over previous
//
#include <hip/hip_runtime.h>
#include <math.h>

// NoisyEmbedding: argmax_j( cos_sim(w[ids[i]], w[j]) + 20*gumbel[i][j] ) -> gather w[argmax]
//
// sims span <= 2 => only j with gumbel g within 0.1 of the ROW max can win
// (20*0.1 = 2). g = -log(-log u) monotone in u => all max/threshold work in
// the u-domain (no transcendentals in the stream). Two-level filter:
//   scan: per 8192-elem chunk, keep survivors within 0.105 of the CHUNK-
//         segment max (bounds list size; ~1.1/chunk) + store segment maxima.
//   score: rebuild ROW max from <=8 chunk maxima, re-filter candidates to
//         within 0.12 of the ROW max (~1.13/row!), exact f32 rescore, argmax
//         with first-index tie-break (matches jnp.argmax), gather.
// Margins: needed gap <= 2/20 = 0.1; row filter 0.12 - ~0.01 u-domain float
// slop >= 0.11 > 0.1 => deterministically a superset. No memsets, no global
// atomics (round-5 lesson: agent-scope RMW on non-coherent XCD L2s = 9x).

constexpr int V  = 50257;
constexpr int D  = 768;
constexpr int BT = 2048;
constexpr long TOTAL = (long)BT * V;            // 102,926,336 (fits int32)
constexpr int ITOTAL = (int)TOTAL;
constexpr int NF4    = ITOTAL >> 2;             // TOTAL % 4 == 0
constexpr int LOG2C  = 13;
constexpr int CHUNK  = 1 << LOG2C;              // 8192 elems per block-chunk
constexpr int NBLK   = (ITOTAL + CHUNK - 1) / CHUNK;  // 12565
constexpr int CCAP   = 16;                      // per-chunk survivor cap (E~1.1)
constexpr int RCAP   = 64;                      // per-row candidate cap (E~1.13)
constexpr float KPOW_SCAN = 1.1107096f;         // expf(0.105)
constexpr float KPOW_ROW  = 1.1274969f;         // expf(0.12)
constexpr float TWO_OVER_EPS = 20.0f;

typedef float f32x4 __attribute__((ext_vector_type(4)));

// --- K1: stream gumbel_u. Per block: segment maxima (chunk straddles <=1 row
//         boundary), store maxima, keep chunk-level survivors. ---
__global__ __launch_bounds__(256) void k_scan(const float* __restrict__ gum,
                                              int* __restrict__ ccnt,
                                              int* __restrict__ cflat,
                                              float* __restrict__ cuv,
                                              float* __restrict__ cmaxlo,
                                              float* __restrict__ cmaxhi) {
  __shared__ float slo[4], shi[4];
  __shared__ float s_tlo, s_thi;
  __shared__ int s_cnt;
  int tid = threadIdx.x, b = blockIdx.x;
  int lane = tid & 63, wid = tid >> 6;
  int start = b * CHUNK;
  int end = start + CHUNK; if (end > ITOTAL) end = ITOTAL;
  int row0 = start / V;                         // compile-time magic-div
  int bnd  = (row0 + 1) * V;
  bool hasHi = end > bnd;

  if (tid == 0) s_cnt = 0;

  const f32x4* g4 = reinterpret_cast<const f32x4*>(gum);
  int f4base = start >> 2;
  f32x4 v[8];
#pragma unroll
  for (int k = 0; k < 8; ++k) {
    int fi = f4base + k * 256 + tid;
    if (fi < NF4) v[k] = __builtin_nontemporal_load(&g4[fi]);
    else          v[k] = (f32x4){-1.f, -1.f, -1.f, -1.f};
  }

  float mlo = -1.f, mhi = -1.f;
  if (hasHi) {                                  // block-uniform branch
#pragma unroll
    for (int k = 0; k < 8; ++k) {
      int e0 = (f4base + k * 256 + tid) << 2;
#pragma unroll
      for (int j = 0; j < 4; ++j) {
        if (e0 + j < bnd) mlo = fmaxf(mlo, v[k][j]);
        else              mhi = fmaxf(mhi, v[k][j]);
      }
    }
  } else {
#pragma unroll
    for (int k = 0; k < 8; ++k)
#pragma unroll
      for (int j = 0; j < 4; ++j) mlo = fmaxf(mlo, v[k][j]);
  }
#pragma unroll
  for (int off = 1; off < 64; off <<= 1) {
    mlo = fmaxf(mlo, __shfl_xor(mlo, off, 64));
    mhi = fmaxf(mhi, __shfl_xor(mhi, off, 64));
  }
  if (lane == 0) { slo[wid] = mlo; shi[wid] = mhi; }
  __syncthreads();                              // also publishes s_cnt = 0
  if (tid == 0) {
    float a = fmaxf(fmaxf(slo[0], slo[1]), fmaxf(slo[2], slo[3]));
    float c = fmaxf(fmaxf(shi[0], shi[1]), fmaxf(shi[2], shi[3]));
    cmaxlo[b] = a;                              // written every call
    cmaxhi[b] = c;                              // -1 if no hi segment
    // g >= g_segmax - 0.105  <=>  u >= u_segmax^KPOW_SCAN (u in (0,1]).
    // Empty hi segment: max=-1 -> NaN threshold -> never used (no hi elems).
    s_tlo = expf(KPOW_SCAN * logf(a));
    s_thi = expf(KPOW_SCAN * logf(c));
  }
  __syncthreads();
  float tlo = s_tlo, thi = s_thi;
#pragma unroll
  for (int k = 0; k < 8; ++k) {
    int e0 = (f4base + k * 256 + tid) << 2;
#pragma unroll
    for (int j = 0; j < 4; ++j) {
      int idx = e0 + j;
      float uu = v[k][j];
      if (uu >= ((idx < bnd) ? tlo : thi)) {    // OOB lanes: -1 -> false
        int p = atomicAdd(&s_cnt, 1);           // LDS atomic, ~1.1 hits/block
        if (p < CCAP) {
          cflat[b * CCAP + p] = idx;
          cuv[b * CCAP + p]   = uu;
        }
      }
    }
  }
  __syncthreads();
  if (tid == 0) ccnt[b] = (s_cnt < CCAP) ? s_cnt : CCAP;  // written every call
}

// --- K2: per row, rebuild row max from chunk maxima, row-filter candidates
//         (~1.13 survive), exact f32 rescore + argmax + gather. ---
__global__ __launch_bounds__(256) void k_score(const float* __restrict__ w,
                                               const int* __restrict__ ids,
                                               const int* __restrict__ ccnt,
                                               const int* __restrict__ cflat,
                                               const float* __restrict__ cuv,
                                               const float* __restrict__ cmaxlo,
                                               const float* __restrict__ cmaxhi,
                                               float* __restrict__ out) {
  __shared__ __align__(16) float q[D];
  __shared__ float lu[RCAP], lsc[RCAP];
  __shared__ int   li[RCAP];
  __shared__ float s_rm[8], s_red[4];
  __shared__ float s_ut, s_invq;
  __shared__ int   s_n, s_sel;
  int row = blockIdx.x;
  int tid = threadIdx.x;
  int lane = tid & 63, wid = tid >> 6;

  int c0 = (row * V) >> LOG2C;
  int c1 = (((row + 1) * V) - 1) >> LOG2C;
  int nch = c1 - c0 + 1;                        // <= 8
  if (tid == 0) s_n = 0;
  if (tid < nch) {
    int c = c0 + tid;
    int row0c = (c * CHUNK) / V;                // magic-div
    s_rm[tid] = (row0c == row) ? cmaxlo[c] : cmaxhi[c];
  }
  // stage q + norm partials (disjoint LDS, overlaps the tiny max loads)
  int qid = ids[row];
  float qs = 0.f;
#pragma unroll
  for (int k = 0; k < 3; ++k) {
    float x = w[(size_t)qid * D + k * 256 + tid];
    q[k * 256 + tid] = x;
    qs += x * x;
  }
#pragma unroll
  for (int off = 32; off > 0; off >>= 1) qs += __shfl_down(qs, off, 64);
  if (lane == 0) s_red[wid] = qs;
  __syncthreads();
  if (tid == 0) {
    float rm = -1.f;
    for (int k = 0; k < nch; ++k) rm = fmaxf(rm, s_rm[k]);
    // row-level: g >= g_rowmax - 0.12  <=>  u >= u_rowmax^KPOW_ROW
    s_ut = expf(KPOW_ROW * logf(rm));
    s_invq = 1.0f / fmaxf(sqrtf(s_red[0] + s_red[1] + s_red[2] + s_red[3]), 1e-12f);
  }
  __syncthreads();
  float ut = s_ut, invq = s_invq;

  if (tid < nch) {                              // collect + row-filter
    int c = c0 + tid;
    int m = ccnt[c]; if (m > CCAP) m = CCAP;
    int lo = row * V, hi = lo + V;
    for (int k = 0; k < m; ++k) {
      int fx = cflat[c * CCAP + k];
      float uu = cuv[c * CCAP + k];
      if (fx >= lo && fx < hi && uu >= ut) {    // ~1.13 survivors per row
        int p = atomicAdd(&s_n, 1);             // LDS atomic
        if (p < RCAP) { li[p] = fx - lo; lu[p] = uu; }
      }
    }
  }
  __syncthreads();
  int n = s_n; if (n > RCAP) n = RCAP;

  for (int cI = wid; cI < n; cI += 4) {         // one wave per candidate
    int j = li[cI];
    const float4* p  = reinterpret_cast<const float4*>(w + (size_t)j * D);
    const float4* qp = reinterpret_cast<const float4*>(q);
    float dot = 0.f, n2 = 0.f;
#pragma unroll
    for (int k = 0; k < 3; ++k) {
      float4 a = p[k * 64 + lane];
      float4 b = qp[k * 64 + lane];
      dot += a.x * b.x + a.y * b.y + a.z * b.z + a.w * b.w;
      n2  += a.x * a.x + a.y * a.y + a.z * a.z + a.w * a.w;
    }
#pragma unroll
    for (int off = 32; off > 0; off >>= 1) {
      dot += __shfl_down(dot, off, 64);
      n2  += __shfl_down(n2,  off, 64);
    }
    if (lane == 0) {
      float invj = 1.0f / fmaxf(sqrtf(n2), 1e-12f);
      lsc[cI] = invq * invj * dot + TWO_OVER_EPS * (-logf(-logf(lu[cI])));
    }
  }
  __syncthreads();

  if (wid == 0) {                               // argmax: (score desc, idx asc)
    float bs = -INFINITY;
    int bj = 0x7fffffff;
    for (int cI = lane; cI < n; cI += 64) {
      float s = lsc[cI];
      int j = li[cI];
      if (s > bs || (s == bs && j < bj)) { bs = s; bj = j; }
    }
#pragma unroll
    for (int off = 32; off > 0; off >>= 1) {
      float os = __shfl_down(bs, off, 64);
      int   oj = __shfl_down(bj, off, 64);
      if (os > bs || (os == bs && oj < bj)) { bs = os; bj = oj; }
    }
    if (lane == 0) s_sel = bj;
  }
  __syncthreads();

  int sel = s_sel;
#pragma unroll
  for (int k = 0; k < 3; ++k)
    out[(size_t)row * D + k * 256 + tid] = w[(size_t)sel * D + k * 256 + tid];
}

extern "C" void kernel_launch(void* const* d_in, const int* in_sizes, int n_in,
                              void* d_out, int out_size, void* d_ws, size_t ws_size,
                              hipStream_t stream) {
  const int*   ids = (const int*)d_in[0];    // input_ids (B*T)
  const float* w   = (const float*)d_in[1];  // weight (V*D)
  const float* gum = (const float*)d_in[2];  // gumbel_u (BT*V)
  float* out = (float*)d_out;

  // ws layout (all fields fully rewritten every call -> no zeroing needed)
  constexpr size_t O_CCNT = 0;
  constexpr size_t O_MLO  = O_CCNT + (size_t)NBLK * 4;
  constexpr size_t O_MHI  = O_MLO  + (size_t)NBLK * 4;
  constexpr size_t O_CFL  = O_MHI  + (size_t)NBLK * 4;
  constexpr size_t O_CUV  = O_CFL  + (size_t)NBLK * CCAP * 4;  // ~1.8 MB total
  char* ws = (char*)d_ws;
  int*   ccnt   = (int*)(ws + O_CCNT);
  float* cmaxlo = (float*)(ws + O_MLO);
  float* cmaxhi = (float*)(ws + O_MHI);
  int*   cflat  = (int*)(ws + O_CFL);
  float* cuv    = (float*)(ws + O_CUV);

  k_scan<<<NBLK, 256, 0, stream>>>(gum, ccnt, cflat, cuv, cmaxlo, cmaxhi);
  k_score<<<BT, 256, 0, stream>>>(w, ids, ccnt, cflat, cuv, cmaxlo, cmaxhi, out);
}